// Round 3
// baseline (140.085 us; speedup 1.0000x reference)
//
#include <hip/hip_runtime.h>
#include <math.h>

#define B_ 2
#define U_ 32
#define V_ 2048
#define IN_ 256
#define ST_ 512
#define H_ 8
#define BU_ 64
#define NR_ 512

// ws layout (float offsets)
#define WS_SLN   0u          // [B][V][IN]      1048576
#define WS_SLNT  1048576u    // [B][IN][V]      1048576
#define WS_SCALE 2097152u    // [BU][2560]      163840  (q:0 k:512 v:768 e:1024 f1:1536 f2:2048)
#define WS_T     2260992u    // [NR][IN]        131072
#define WS_CB    2392064u    // [NR]            512
#define WS_SSUMP 2392576u    // [NR][8]         4096
#define WS_CTXP  2396672u    // [8][NR][IN]     1048576
#define WS_AO    3445248u    // [BU][512]       32768
#define WS_H2    3478016u    // [BU][512]       32768

__device__ __forceinline__ float wsum(float v){
  #pragma unroll
  for(int m=32;m>0;m>>=1) v += __shfl_xor(v, m, 64);
  return v;
}

// ---------------- K1: fused sender-LN+transpose (blocks 0..127) and scales GEMM (blocks 128..447) ----------------
__global__ __launch_bounds__(256) void k_pre(const float* __restrict__ snd,
    const float* __restrict__ g, const float* __restrict__ bb,
    const float* __restrict__ codes,
    const float* __restrict__ Cq, const float* __restrict__ Ck, const float* __restrict__ Cv,
    const float* __restrict__ Ce, const float* __restrict__ C1, const float* __restrict__ C2,
    float* __restrict__ ws){
  __shared__ float tile[32][261];
  __shared__ float cds[8][256];
  const int tid = threadIdx.x;
  if(blockIdx.x < 128){
    const int wave = tid>>6, lane = tid&63;
    const int rowbase = blockIdx.x * 32;
    const int b = rowbase >> 11, vloc = rowbase & 2047;
    float4 gg  = *(const float4*)(g  + lane*4);
    float4 bbv = *(const float4*)(bb + lane*4);
    for(int it=0; it<8; ++it){
      int rl = it*4 + wave;
      int r  = rowbase + rl;
      float4 x = *(const float4*)(snd + (size_t)r*IN_ + lane*4);
      float s = x.x+x.y+x.z+x.w;
      float q = x.x*x.x+x.y*x.y+x.z*x.z+x.w*x.w;
      s = wsum(s); q = wsum(q);
      float mu = s*(1.0f/256.0f);
      float rv = rsqrtf(q*(1.0f/256.0f) - mu*mu + 1e-5f);
      float4 y;
      y.x = (x.x-mu)*rv*gg.x + bbv.x;
      y.y = (x.y-mu)*rv*gg.y + bbv.y;
      y.z = (x.z-mu)*rv*gg.z + bbv.z;
      y.w = (x.w-mu)*rv*gg.w + bbv.w;
      *(float4*)(ws + WS_SLN + (size_t)r*IN_ + lane*4) = y;
      tile[rl][lane*4+0] = y.x;
      tile[rl][lane*4+1] = y.y;
      tile[rl][lane*4+2] = y.z;
      tile[rl][lane*4+3] = y.w;
    }
    __syncthreads();
    const int vh = tid & 31;
    const int ibase = (tid >> 5);
    for(int it=0; it<32; ++it){
      int i = it*8 + ibase;
      ws[WS_SLNT + ((size_t)b*IN_ + i)*V_ + vloc + vh] = tile[vh][i];
    }
  } else {
    const int idx = blockIdx.x - 128;
    const int cg = idx % 40, bg = idx / 40;
    #pragma unroll
    for(int j=0;j<8;++j){
      int fi = j*256 + tid;
      cds[fi>>8][fi&255] = codes[(size_t)(bg*8)*256 + fi];
    }
    __syncthreads();
    const int q = tid & 3;
    const int col = cg*64 + (tid >> 2);
    const float* Cp; int loc;
    if(col < 512){ Cp = Cq; loc = col; }
    else if(col < 768){ Cp = Ck; loc = col - 512; }
    else if(col < 1024){ Cp = Cv; loc = col - 768; }
    else if(col < 1536){ Cp = Ce; loc = col - 1024; }
    else if(col < 2048){ Cp = C1; loc = col - 1536; }
    else { Cp = C2; loc = col - 2048; }
    const float4* wrow = (const float4*)(Cp + (size_t)loc*256 + q*64);
    float acc[8] = {0,0,0,0,0,0,0,0};
    #pragma unroll 4
    for(int i=0;i<16;++i){
      float4 w = wrow[i];
      #pragma unroll
      for(int k=0;k<8;++k){
        const float4 c = *(const float4*)(&cds[k][q*64 + i*4]);
        acc[k] += w.x*c.x + w.y*c.y + w.z*c.z + w.w*c.w;
      }
    }
    #pragma unroll
    for(int k=0;k<8;++k){
      acc[k] += __shfl_xor(acc[k], 1, 64);
      acc[k] += __shfl_xor(acc[k], 2, 64);
    }
    ws[WS_SCALE + (size_t)(bg*8 + q)*2560 + col]     = 1.0f + acc[q];
    ws[WS_SCALE + (size_t)(bg*8 + q + 4)*2560 + col] = 1.0f + acc[q+4];
  }
}

// ---------------- K2: receiver LN + q head-slice + t_k + cb (512 blocks = bu x h) ----------------
__global__ __launch_bounds__(256) void k_qt(const float* __restrict__ rst,
    const float* __restrict__ lg, const float* __restrict__ lb,
    const float* __restrict__ Wq, const float* __restrict__ bq,
    const float* __restrict__ Wk, const float* __restrict__ bk,
    float* __restrict__ ws){
  const int bu = blockIdx.x >> 3, h = blockIdx.x & 7;
  const int b = bu >> 5, u = bu & 31;
  const int r = (b*8 + h)*32 + u;
  const int tid = threadIdx.x, wave = tid>>6, lane = tid&63;
  __shared__ float xm[512];
  __shared__ float qv[64];
  __shared__ float red[4][65];
  __shared__ float rsm[4], rqm[4];
  float2 x2 = *(const float2*)(rst + (size_t)bu*512 + tid*2);
  float s = x2.x + x2.y, q = x2.x*x2.x + x2.y*x2.y;
  s = wsum(s); q = wsum(q);
  if(lane==0){ rsm[wave] = s; rqm[wave] = q; }
  __syncthreads();
  float S = rsm[0]+rsm[1]+rsm[2]+rsm[3];
  float Q = rqm[0]+rqm[1]+rqm[2]+rqm[3];
  float mu = S*(1.0f/512.0f);
  float rv = rsqrtf(Q*(1.0f/512.0f) - mu*mu + 1e-5f);
  const float* scal = ws + WS_SCALE + (size_t)bu*2560;
  xm[tid*2]   = ((x2.x-mu)*rv*lg[tid*2]   + lb[tid*2])   * scal[tid*2];
  xm[tid*2+1] = ((x2.y-mu)*rv*lg[tid*2+1] + lb[tid*2+1]) * scal[tid*2+1];
  __syncthreads();
  {
    const int o = tid & 63, sp = tid >> 6;
    const float4* wq = (const float4*)(Wq + (size_t)(h*64 + o)*512 + sp*128);
    const float* xp = xm + sp*128;
    float acc = 0.f;
    #pragma unroll 8
    for(int c4=0;c4<32;++c4){
      float4 w = wq[c4];
      acc += w.x*xp[c4*4] + w.y*xp[c4*4+1] + w.z*xp[c4*4+2] + w.w*xp[c4*4+3];
    }
    red[sp][o] = acc;
  }
  __syncthreads();
  if(tid < 64)
    qv[tid] = red[0][tid]+red[1][tid]+red[2][tid]+red[3][tid] + bq[h*64+tid];
  __syncthreads();
  if(tid < 64){
    float p = qv[tid] * bk[h*64+tid];
    p = wsum(p);
    if(tid==0) ws[WS_CB + r] = p;
  }
  {
    float acc = 0.f;
    #pragma unroll 4
    for(int d=0; d<64; ++d)
      acc += qv[d] * Wk[(size_t)(h*64+d)*256 + tid];
    ws[WS_T + (size_t)r*256 + tid] = acc * scal[512 + tid];
  }
}

// ---------------- K3: fused scores->exp->ctx, 512 blocks x 512 thr, wave = 1 row ----------------
__global__ __launch_bounds__(512) void k_scctx(float* __restrict__ ws){
  const int rg = blockIdx.x >> 3, vc = blockIdx.x & 7;  // 64 rowgroups(8) x 8 vchunks(256)
  const int tid = threadIdx.x, lane = tid & 63;
  const int w = __builtin_amdgcn_readfirstlane(tid >> 6); // wave 0..7 -> row
  const int r0 = rg*8;
  const int b = rg >> 5;
  __shared__ float Tl[8][256];
  __shared__ float P[8][256];
  {
    const float4* src = (const float4*)(ws + WS_T + (size_t)r0*256);
    ((float4*)&Tl[0][0])[tid] = src[tid];
  }
  __syncthreads();
  const int r = r0 + w;
  // ---- phase 1: scores row + exp ----
  const float* sT = ws + WS_SLNT + (size_t)b*IN_*V_ + vc*256 + lane*4;
  float4 a = {0,0,0,0};
  #pragma unroll 2
  for(int i4=0;i4<64;++i4){
    float4 tv = *(const float4*)(&Tl[w][i4*4]);
    float4 s0 = *(const float4*)(sT + (size_t)(i4*4+0)*V_);
    float4 s1 = *(const float4*)(sT + (size_t)(i4*4+1)*V_);
    float4 s2 = *(const float4*)(sT + (size_t)(i4*4+2)*V_);
    float4 s3 = *(const float4*)(sT + (size_t)(i4*4+3)*V_);
    a.x += tv.x*s0.x; a.y += tv.x*s0.y; a.z += tv.x*s0.z; a.w += tv.x*s0.w;
    a.x += tv.y*s1.x; a.y += tv.y*s1.y; a.z += tv.y*s1.z; a.w += tv.y*s1.w;
    a.x += tv.z*s2.x; a.y += tv.z*s2.y; a.z += tv.z*s2.z; a.w += tv.z*s2.w;
    a.x += tv.w*s3.x; a.y += tv.w*s3.y; a.z += tv.w*s3.z; a.w += tv.w*s3.w;
  }
  const float cb = ws[WS_CB + r];
  float4 e;
  e.x = __expf((a.x+cb)*0.125f); e.y = __expf((a.y+cb)*0.125f);
  e.z = __expf((a.z+cb)*0.125f); e.w = __expf((a.w+cb)*0.125f);
  *(float4*)(&P[w][lane*4]) = e;
  float ss = wsum(e.x+e.y+e.z+e.w);
  if(lane==0) ws[WS_SSUMP + (size_t)r*8 + vc] = ss;
  // ---- phase 2: ctx partial (wave reads only its own P row; wave-synchronous) ----
  const float* SL = ws + WS_SLN + ((size_t)b*V_ + vc*256)*IN_ + lane*4;
  float4 c = {0,0,0,0};
  #pragma unroll 2
  for(int v4=0;v4<64;++v4){
    float4 pv = *(const float4*)(&P[w][v4*4]);
    float4 x0 = *(const float4*)(SL + (size_t)(v4*4+0)*IN_);
    float4 x1 = *(const float4*)(SL + (size_t)(v4*4+1)*IN_);
    float4 x2 = *(const float4*)(SL + (size_t)(v4*4+2)*IN_);
    float4 x3 = *(const float4*)(SL + (size_t)(v4*4+3)*IN_);
    c.x += pv.x*x0.x; c.y += pv.x*x0.y; c.z += pv.x*x0.z; c.w += pv.x*x0.w;
    c.x += pv.y*x1.x; c.y += pv.y*x1.y; c.z += pv.y*x1.z; c.w += pv.y*x1.w;
    c.x += pv.z*x2.x; c.y += pv.z*x2.y; c.z += pv.z*x2.z; c.w += pv.z*x2.w;
    c.x += pv.w*x3.x; c.y += pv.w*x3.y; c.z += pv.w*x3.z; c.w += pv.w*x3.w;
  }
  *(float4*)(ws + WS_CTXP + ((size_t)vc*NR_ + r)*IN_ + lane*4) = c;
}

// ---------------- K4: merged msg+exit (256 blocks = bu x st, 512 thr) ----------------
__global__ __launch_bounds__(512) void k_mexit(const float* __restrict__ Wv, const float* __restrict__ bv,
    const float* __restrict__ We, const float* __restrict__ be,
    const float* __restrict__ lsa, float* __restrict__ ws){
  const int bu = blockIdx.x >> 2, st = blockIdx.x & 3;
  const int b = bu >> 5, u = bu & 31;
  const int tid = threadIdx.x;
  __shared__ float xs[8][256];
  __shared__ float m2[512];
  __shared__ float invS[8];
  __shared__ float ps[4][128];
  // invS per head (wave 0)
  if(tid < 64){
    int h = tid>>3, k = tid&7;
    int r = (b*8+h)*32 + u;
    float v = ws[WS_SSUMP + (size_t)r*8 + k];
    v += __shfl_xor(v,1,64); v += __shfl_xor(v,2,64); v += __shfl_xor(v,4,64);
    if(k==0) invS[h] = 1.0f / v;
  }
  // phase A: xs[h][i] = (sum_vc CTXP) * scale_v  (invS deferred, linear)
  {
    const int h = tid >> 6, i4 = tid & 63;
    const int r = (b*8+h)*32 + u;
    float4 s = {0,0,0,0};
    #pragma unroll
    for(int vcx=0; vcx<8; ++vcx){
      float4 t = *(const float4*)(ws + WS_CTXP + ((size_t)vcx*NR_ + r)*IN_ + i4*4);
      s.x += t.x; s.y += t.y; s.z += t.z; s.w += t.w;
    }
    float4 sc = *(const float4*)(ws + WS_SCALE + (size_t)bu*2560 + 768 + i4*4);
    s.x *= sc.x; s.y *= sc.y; s.z *= sc.z; s.w *= sc.w;
    *(float4*)(&xs[h][i4*4]) = s;
  }
  __syncthreads();
  // phase B: m2[tid] = (Wv[tid]·xs[h] * invS[h] + bv)*scale_e
  {
    const int h = tid >> 6;
    const float4* wv = (const float4*)(Wv + (size_t)tid*256);
    const float* xp = &xs[h][0];
    float acc = 0.f;
    #pragma unroll 8
    for(int c4=0;c4<64;++c4){
      float4 w = wv[c4];
      acc += w.x*xp[c4*4]+w.y*xp[c4*4+1]+w.z*xp[c4*4+2]+w.w*xp[c4*4+3];
    }
    m2[tid] = (acc*invS[h] + bv[tid]) * ws[WS_SCALE + (size_t)bu*2560 + 1024 + tid];
  }
  __syncthreads();
  // phase C: quarter of We matvec, 4-way K split
  {
    const int s = st*128 + (tid & 127), sp = tid >> 7;
    const float4* we = (const float4*)(We + (size_t)s*512 + sp*128);
    const float* mp = m2 + sp*128;
    float acc = 0.f;
    #pragma unroll 8
    for(int c4=0;c4<32;++c4){
      float4 w = we[c4];
      acc += w.x*mp[c4*4]+w.y*mp[c4*4+1]+w.z*mp[c4*4+2]+w.w*mp[c4*4+3];
    }
    ps[sp][tid&127] = acc;
  }
  __syncthreads();
  if(tid < 128){
    const int s = st*128 + tid;
    ws[WS_AO + (size_t)bu*512 + s] =
      (ps[0][tid]+ps[1][tid]+ps[2][tid]+ps[3][tid] + be[s]) * lsa[s];
  }
}

// ---------------- K5: FFN layernorm + W1 + gelu + scale2 (256 blocks) ----------------
__global__ __launch_bounds__(256) void k_ffn1(const float* __restrict__ lg, const float* __restrict__ lb,
    const float* __restrict__ W1, const float* __restrict__ b1, float* __restrict__ ws){
  const int bu = blockIdx.x >> 2, ot = blockIdx.x & 3;
  const int tid = threadIdx.x, wave = tid>>6, lane = tid&63;
  __shared__ float xr[512];
  __shared__ float rsm[4], rqm[4];
  __shared__ float ps[2][128];
  float2 x2 = *(const float2*)(ws + WS_AO + (size_t)bu*512 + tid*2);
  float s = x2.x+x2.y, q = x2.x*x2.x+x2.y*x2.y;
  s = wsum(s); q = wsum(q);
  if(lane==0){ rsm[wave]=s; rqm[wave]=q; }
  __syncthreads();
  float S=rsm[0]+rsm[1]+rsm[2]+rsm[3], Q=rqm[0]+rqm[1]+rqm[2]+rqm[3];
  float mu = S*(1.0f/512.0f);
  float rv = rsqrtf(Q*(1.0f/512.0f) - mu*mu + 1e-5f);
  const float* scal = ws + WS_SCALE + (size_t)bu*2560;
  xr[tid*2]   = ((x2.x-mu)*rv*lg[tid*2]   + lb[tid*2])   * scal[1536 + tid*2];
  xr[tid*2+1] = ((x2.y-mu)*rv*lg[tid*2+1] + lb[tid*2+1]) * scal[1536 + tid*2+1];
  __syncthreads();
  const int o = ot*128 + (tid & 127), sp = tid >> 7;
  const float4* w1 = (const float4*)(W1 + (size_t)o*512 + sp*256);
  const float* xp = xr + sp*256;
  float acc = 0.f;
  #pragma unroll 8
  for(int c4=0;c4<64;++c4){
    float4 w = w1[c4];
    acc += w.x*xp[c4*4]+w.y*xp[c4*4+1]+w.z*xp[c4*4+2]+w.w*xp[c4*4+3];
  }
  ps[sp][tid&127] = acc;
  __syncthreads();
  if(sp==0){
    float hh = ps[0][tid] + ps[1][tid] + b1[o];
    float ge = 0.5f*hh*(1.0f + erff(hh*0.70710678118654752f));
    ws[WS_H2 + (size_t)bu*512 + o] = ge * scal[2048 + o];
  }
}

// ---------------- K6: FFN W2 + residual -> out (256 blocks) ----------------
__global__ __launch_bounds__(256) void k_ffn2(const float* __restrict__ W2, const float* __restrict__ b2,
    const float* __restrict__ lsf, const float* __restrict__ ws, float* __restrict__ out){
  const int bu = blockIdx.x >> 2, st = blockIdx.x & 3;
  const int tid = threadIdx.x;
  const int s = st*128 + (tid & 127), sp = tid >> 7;
  __shared__ float ps[2][128];
  const float4* w2 = (const float4*)(W2 + (size_t)s*512 + sp*256);
  const float* hp = ws + WS_H2 + (size_t)bu*512 + sp*256;
  float acc = 0.f;
  #pragma unroll 8
  for(int c4=0;c4<64;++c4){
    float4 w = w2[c4];
    acc += w.x*hp[c4*4]+w.y*hp[c4*4+1]+w.z*hp[c4*4+2]+w.w*hp[c4*4+3];
  }
  ps[sp][tid&127] = acc;
  __syncthreads();
  if(sp==0)
    out[(size_t)bu*512 + s] = ws[WS_AO + (size_t)bu*512 + s]
                            + (ps[0][tid]+ps[1][tid] + b2[s]) * lsf[s];
}

extern "C" void kernel_launch(void* const* d_in, const int* in_sizes, int n_in,
                              void* d_out, int out_size, void* d_ws, size_t ws_size,
                              hipStream_t stream) {
  (void)in_sizes; (void)n_in; (void)out_size; (void)ws_size;
  const float* rst   = (const float*)d_in[0];
  const float* codes = (const float*)d_in[2];
  const float* snd   = (const float*)d_in[3];
  const float* ln_s_g = (const float*)d_in[4];
  const float* ln_s_b = (const float*)d_in[5];
  const float* ln_r_g = (const float*)d_in[6];
  const float* ln_r_b = (const float*)d_in[7];
  const float* Wq = (const float*)d_in[8];
  const float* bq = (const float*)d_in[9];
  const float* Cq = (const float*)d_in[10];
  const float* Wk = (const float*)d_in[11];
  const float* bk = (const float*)d_in[12];
  const float* Ck = (const float*)d_in[13];
  const float* Wv = (const float*)d_in[14];
  const float* bv = (const float*)d_in[15];
  const float* Cv = (const float*)d_in[16];
  const float* We = (const float*)d_in[17];
  const float* be = (const float*)d_in[18];
  const float* Ce = (const float*)d_in[19];
  const float* lsa = (const float*)d_in[20];
  const float* ln_f_g = (const float*)d_in[21];
  const float* ln_f_b = (const float*)d_in[22];
  const float* W1 = (const float*)d_in[23];
  const float* b1 = (const float*)d_in[24];
  const float* C1 = (const float*)d_in[25];
  const float* W2 = (const float*)d_in[26];
  const float* b2 = (const float*)d_in[27];
  const float* C2 = (const float*)d_in[28];
  const float* lsf = (const float*)d_in[29];
  float* ws  = (float*)d_ws;
  float* out = (float*)d_out;

  k_pre   <<<448, 256, 0, stream>>>(snd, ln_s_g, ln_s_b, codes, Cq, Ck, Cv, Ce, C1, C2, ws);
  k_qt    <<<512, 256, 0, stream>>>(rst, ln_r_g, ln_r_b, Wq, bq, Wk, bk, ws);
  k_scctx <<<512, 512, 0, stream>>>(ws);
  k_mexit <<<256, 512, 0, stream>>>(Wv, bv, We, be, lsa, ws);
  k_ffn1  <<<256, 256, 0, stream>>>(ln_f_g, ln_f_b, W1, b1, ws);
  k_ffn2  <<<256, 256, 0, stream>>>(W2, b2, lsf, ws, out);
}

// Round 4
// 102.273 us; speedup vs baseline: 1.3697x; 1.3697x over previous
//
#include <hip/hip_runtime.h>
#include <math.h>

#define B_ 2
#define U_ 32
#define V_ 2048
#define IN_ 256
#define ST_ 512
#define H_ 8
#define BU_ 64
#define NR_ 512

// ws layout (float offsets)
#define WS_SLN   0u          // [B][V][IN]      1048576
#define WS_SLNT  1048576u    // [B][IN][V]      1048576
#define WS_SCALE 2097152u    // [BU][2560]      163840  (q:0 k:512 v:768 e:1024 f1:1536 f2:2048)
#define WS_T     2260992u    // [NR][IN]        131072
#define WS_CB    2392064u    // [NR]            512
#define WS_SSUMP 2392576u    // [NR][8]         4096
#define WS_CTXP  2396672u    // [8][NR][IN]     1048576
#define WS_AO    3445248u    // [BU][512]       32768
#define WS_H2    3478016u    // [BU][512]       32768

__device__ __forceinline__ float wsum(float v){
  #pragma unroll
  for(int m=32;m>0;m>>=1) v += __shfl_xor(v, m, 64);
  return v;
}

#define FMA4(A, t, S) { A.x += (t)*(S).x; A.y += (t)*(S).y; A.z += (t)*(S).z; A.w += (t)*(S).w; }

// ---------------- K1: fused sender-LN+transpose (blocks 0..127) and scales GEMM (blocks 128..447) ----------------
__global__ __launch_bounds__(256) void k_pre(const float* __restrict__ snd,
    const float* __restrict__ g, const float* __restrict__ bb,
    const float* __restrict__ codes,
    const float* __restrict__ Cq, const float* __restrict__ Ck, const float* __restrict__ Cv,
    const float* __restrict__ Ce, const float* __restrict__ C1, const float* __restrict__ C2,
    float* __restrict__ ws){
  __shared__ float tile[32][261];
  __shared__ float cds[8][256];
  const int tid = threadIdx.x;
  if(blockIdx.x < 128){
    const int wave = tid>>6, lane = tid&63;
    const int rowbase = blockIdx.x * 32;
    const int b = rowbase >> 11, vloc = rowbase & 2047;
    float4 gg  = *(const float4*)(g  + lane*4);
    float4 bbv = *(const float4*)(bb + lane*4);
    for(int it=0; it<8; ++it){
      int rl = it*4 + wave;
      int r  = rowbase + rl;
      float4 x = *(const float4*)(snd + (size_t)r*IN_ + lane*4);
      float s = x.x+x.y+x.z+x.w;
      float q = x.x*x.x+x.y*x.y+x.z*x.z+x.w*x.w;
      s = wsum(s); q = wsum(q);
      float mu = s*(1.0f/256.0f);
      float rv = rsqrtf(q*(1.0f/256.0f) - mu*mu + 1e-5f);
      float4 y;
      y.x = (x.x-mu)*rv*gg.x + bbv.x;
      y.y = (x.y-mu)*rv*gg.y + bbv.y;
      y.z = (x.z-mu)*rv*gg.z + bbv.z;
      y.w = (x.w-mu)*rv*gg.w + bbv.w;
      *(float4*)(ws + WS_SLN + (size_t)r*IN_ + lane*4) = y;
      tile[rl][lane*4+0] = y.x;
      tile[rl][lane*4+1] = y.y;
      tile[rl][lane*4+2] = y.z;
      tile[rl][lane*4+3] = y.w;
    }
    __syncthreads();
    const int vh = tid & 31;
    const int ibase = (tid >> 5);
    for(int it=0; it<32; ++it){
      int i = it*8 + ibase;
      ws[WS_SLNT + ((size_t)b*IN_ + i)*V_ + vloc + vh] = tile[vh][i];
    }
  } else {
    const int idx = blockIdx.x - 128;
    const int cg = idx % 40, bg = idx / 40;
    #pragma unroll
    for(int j=0;j<8;++j){
      int fi = j*256 + tid;
      cds[fi>>8][fi&255] = codes[(size_t)(bg*8)*256 + fi];
    }
    __syncthreads();
    const int q = tid & 3;
    const int col = cg*64 + (tid >> 2);
    const float* Cp; int loc;
    if(col < 512){ Cp = Cq; loc = col; }
    else if(col < 768){ Cp = Ck; loc = col - 512; }
    else if(col < 1024){ Cp = Cv; loc = col - 768; }
    else if(col < 1536){ Cp = Ce; loc = col - 1024; }
    else if(col < 2048){ Cp = C1; loc = col - 1536; }
    else { Cp = C2; loc = col - 2048; }
    const float4* wrow = (const float4*)(Cp + (size_t)loc*256 + q*64);
    float acc[8] = {0,0,0,0,0,0,0,0};
    #pragma unroll 4
    for(int i=0;i<16;++i){
      float4 w = wrow[i];
      #pragma unroll
      for(int k=0;k<8;++k){
        const float4 c = *(const float4*)(&cds[k][q*64 + i*4]);
        acc[k] += w.x*c.x + w.y*c.y + w.z*c.z + w.w*c.w;
      }
    }
    #pragma unroll
    for(int k=0;k<8;++k){
      acc[k] += __shfl_xor(acc[k], 1, 64);
      acc[k] += __shfl_xor(acc[k], 2, 64);
    }
    ws[WS_SCALE + (size_t)(bg*8 + q)*2560 + col]     = 1.0f + acc[q];
    ws[WS_SCALE + (size_t)(bg*8 + q + 4)*2560 + col] = 1.0f + acc[q+4];
  }
}

// ---------------- K2: receiver LN + q head-slice + t_k + cb (512 blocks = bu x h) ----------------
__global__ __launch_bounds__(256) void k_qt(const float* __restrict__ rst,
    const float* __restrict__ lg, const float* __restrict__ lb,
    const float* __restrict__ Wq, const float* __restrict__ bq,
    const float* __restrict__ Wk, const float* __restrict__ bk,
    float* __restrict__ ws){
  const int bu = blockIdx.x >> 3, h = blockIdx.x & 7;
  const int b = bu >> 5, u = bu & 31;
  const int r = (b*8 + h)*32 + u;
  const int tid = threadIdx.x, wave = tid>>6, lane = tid&63;
  __shared__ float xm[512];
  __shared__ float qv[64];
  __shared__ float red[4][65];
  __shared__ float rsm[4], rqm[4];
  float2 x2 = *(const float2*)(rst + (size_t)bu*512 + tid*2);
  float s = x2.x + x2.y, q = x2.x*x2.x + x2.y*x2.y;
  s = wsum(s); q = wsum(q);
  if(lane==0){ rsm[wave] = s; rqm[wave] = q; }
  __syncthreads();
  float S = rsm[0]+rsm[1]+rsm[2]+rsm[3];
  float Q = rqm[0]+rqm[1]+rqm[2]+rqm[3];
  float mu = S*(1.0f/512.0f);
  float rv = rsqrtf(Q*(1.0f/512.0f) - mu*mu + 1e-5f);
  const float* scal = ws + WS_SCALE + (size_t)bu*2560;
  xm[tid*2]   = ((x2.x-mu)*rv*lg[tid*2]   + lb[tid*2])   * scal[tid*2];
  xm[tid*2+1] = ((x2.y-mu)*rv*lg[tid*2+1] + lb[tid*2+1]) * scal[tid*2+1];
  __syncthreads();
  {
    const int o = tid & 63, sp = tid >> 6;
    const float4* wq = (const float4*)(Wq + (size_t)(h*64 + o)*512 + sp*128);
    const float* xp = xm + sp*128;
    float acc = 0.f;
    #pragma unroll 8
    for(int c4=0;c4<32;++c4){
      float4 w = wq[c4];
      acc += w.x*xp[c4*4] + w.y*xp[c4*4+1] + w.z*xp[c4*4+2] + w.w*xp[c4*4+3];
    }
    red[sp][o] = acc;
  }
  __syncthreads();
  if(tid < 64)
    qv[tid] = red[0][tid]+red[1][tid]+red[2][tid]+red[3][tid] + bq[h*64+tid];
  __syncthreads();
  if(tid < 64){
    float p = qv[tid] * bk[h*64+tid];
    p = wsum(p);
    if(tid==0) ws[WS_CB + r] = p;
  }
  {
    float acc = 0.f;
    #pragma unroll 4
    for(int d=0; d<64; ++d)
      acc += qv[d] * Wk[(size_t)(h*64+d)*256 + tid];
    ws[WS_T + (size_t)r*256 + tid] = acc * scal[512 + tid];
  }
}

// ---------------- K3: fused scores->exp->ctx, LDS-staged. 256 blocks x 512 thr ----------------
// block: 16 rows x 256 v. waves: wr(0..3) = row quad, wk(0..1) = K half.
__global__ __launch_bounds__(512) void k_scctx(float* __restrict__ ws){
  const int bid = blockIdx.x;
  const int rg = bid >> 3, vc = bid & 7;   // 32 rowgroups(16 rows) x 8 vchunks(256)
  const int r0 = rg * 16;
  const int b  = rg >> 4;
  const int v0 = vc * 256;
  const int tid = threadIdx.x, lane = tid & 63;
  const int w  = __builtin_amdgcn_readfirstlane(tid >> 6);
  const int wr = w & 3, wk = w >> 2;
  const int rw = wr*4;                 // local row base of this wave
  const int i0 = lane * 4;             // lane's float4 column (v in ph1, i in ph2)
  const int srow = tid >> 6;           // staging row 0..7
  const int sf   = (tid & 63) * 4;     // staging col

  __shared__ float T[16][256];         // 16KB: T rows (ph1); reused as D-partial (ph2)
  __shared__ float P[16][256];         // 16KB: exp(scores); doubles as score-partial buffer
  __shared__ float stg[32][256];       // 32KB: staged sT slice (ph1) / SL slice (ph2)

  // stage T rows (16 x 256 = 1024 float4, 512 thr -> 2 each)
  {
    const float4* src = (const float4*)(ws + WS_T + (size_t)r0*256);
    float4* dst = (float4*)&T[0][0];
    dst[tid]       = src[tid];
    dst[512 + tid] = src[512 + tid];
  }

  // ================= phase 1: scores = T x sT =================
  float4 a0={0,0,0,0}, a1={0,0,0,0}, a2={0,0,0,0}, a3={0,0,0,0};
  const float* p1base = ws + WS_SLNT + (size_t)b*IN_*V_ + v0;
  float4 g0, g1, g2, g3;
  g0 = *(const float4*)(p1base + (size_t)(srow     )*V_ + sf);
  g1 = *(const float4*)(p1base + (size_t)(srow +  8)*V_ + sf);
  g2 = *(const float4*)(p1base + (size_t)(srow + 16)*V_ + sf);
  g3 = *(const float4*)(p1base + (size_t)(srow + 24)*V_ + sf);
  for(int s=0; s<8; ++s){
    __syncthreads();                       // stg free
    *(float4*)&stg[srow   ][sf] = g0;
    *(float4*)&stg[srow+ 8][sf] = g1;
    *(float4*)&stg[srow+16][sf] = g2;
    *(float4*)&stg[srow+24][sf] = g3;
    if(s < 7){
      const float* nb = p1base + (size_t)(s+1)*32*V_;
      g0 = *(const float4*)(nb + (size_t)(srow     )*V_ + sf);
      g1 = *(const float4*)(nb + (size_t)(srow +  8)*V_ + sf);
      g2 = *(const float4*)(nb + (size_t)(srow + 16)*V_ + sf);
      g3 = *(const float4*)(nb + (size_t)(srow + 24)*V_ + sf);
    }
    __syncthreads();                       // stg ready
    #pragma unroll
    for(int kk=0; kk<4; ++kk){
      const int kl = wk*16 + kk*4;         // local k in slice
      const int ig = s*32 + kl;            // global i
      float4 t0 = *(const float4*)&T[rw+0][ig];
      float4 t1 = *(const float4*)&T[rw+1][ig];
      float4 t2 = *(const float4*)&T[rw+2][ig];
      float4 t3 = *(const float4*)&T[rw+3][ig];
      float4 s0v = *(const float4*)&stg[kl+0][i0];
      float4 s1v = *(const float4*)&stg[kl+1][i0];
      float4 s2v = *(const float4*)&stg[kl+2][i0];
      float4 s3v = *(const float4*)&stg[kl+3][i0];
      FMA4(a0, t0.x, s0v) FMA4(a0, t0.y, s1v) FMA4(a0, t0.z, s2v) FMA4(a0, t0.w, s3v)
      FMA4(a1, t1.x, s0v) FMA4(a1, t1.y, s1v) FMA4(a1, t1.z, s2v) FMA4(a1, t1.w, s3v)
      FMA4(a2, t2.x, s0v) FMA4(a2, t2.y, s1v) FMA4(a2, t2.z, s2v) FMA4(a2, t2.w, s3v)
      FMA4(a3, t3.x, s0v) FMA4(a3, t3.y, s1v) FMA4(a3, t3.z, s2v) FMA4(a3, t3.w, s3v)
    }
  }
  // reduce K halves through P, then exp (wk0 finishes)
  if(wk == 1){
    *(float4*)&P[rw+0][i0] = a0;
    *(float4*)&P[rw+1][i0] = a1;
    *(float4*)&P[rw+2][i0] = a2;
    *(float4*)&P[rw+3][i0] = a3;
  }
  __syncthreads();
  if(wk == 0){
    const int r = r0 + rw;
    float4 q0 = *(const float4*)&P[rw+0][i0];
    float4 q1 = *(const float4*)&P[rw+1][i0];
    float4 q2 = *(const float4*)&P[rw+2][i0];
    float4 q3 = *(const float4*)&P[rw+3][i0];
    float cb0 = ws[WS_CB + r+0], cb1 = ws[WS_CB + r+1];
    float cb2 = ws[WS_CB + r+2], cb3 = ws[WS_CB + r+3];
    float4 e;
    e.x = __expf((a0.x+q0.x+cb0)*0.125f); e.y = __expf((a0.y+q0.y+cb0)*0.125f);
    e.z = __expf((a0.z+q0.z+cb0)*0.125f); e.w = __expf((a0.w+q0.w+cb0)*0.125f);
    *(float4*)&P[rw+0][i0] = e;
    float ss = wsum(e.x+e.y+e.z+e.w);
    if(lane==0) ws[WS_SSUMP + (size_t)(r+0)*8 + vc] = ss;
    e.x = __expf((a1.x+q1.x+cb1)*0.125f); e.y = __expf((a1.y+q1.y+cb1)*0.125f);
    e.z = __expf((a1.z+q1.z+cb1)*0.125f); e.w = __expf((a1.w+q1.w+cb1)*0.125f);
    *(float4*)&P[rw+1][i0] = e;
    ss = wsum(e.x+e.y+e.z+e.w);
    if(lane==0) ws[WS_SSUMP + (size_t)(r+1)*8 + vc] = ss;
    e.x = __expf((a2.x+q2.x+cb2)*0.125f); e.y = __expf((a2.y+q2.y+cb2)*0.125f);
    e.z = __expf((a2.z+q2.z+cb2)*0.125f); e.w = __expf((a2.w+q2.w+cb2)*0.125f);
    *(float4*)&P[rw+2][i0] = e;
    ss = wsum(e.x+e.y+e.z+e.w);
    if(lane==0) ws[WS_SSUMP + (size_t)(r+2)*8 + vc] = ss;
    e.x = __expf((a3.x+q3.x+cb3)*0.125f); e.y = __expf((a3.y+q3.y+cb3)*0.125f);
    e.z = __expf((a3.z+q3.z+cb3)*0.125f); e.w = __expf((a3.w+q3.w+cb3)*0.125f);
    *(float4*)&P[rw+3][i0] = e;
    ss = wsum(e.x+e.y+e.z+e.w);
    if(lane==0) ws[WS_SSUMP + (size_t)(r+3)*8 + vc] = ss;
  }

  // ================= phase 2: ctx_partial = P x SL =================
  float4 d0={0,0,0,0}, d1={0,0,0,0}, d2={0,0,0,0}, d3={0,0,0,0};
  const float* p2base = ws + WS_SLN + ((size_t)b*V_ + v0)*IN_;
  g0 = *(const float4*)(p2base + (size_t)(srow     )*IN_ + sf);
  g1 = *(const float4*)(p2base + (size_t)(srow +  8)*IN_ + sf);
  g2 = *(const float4*)(p2base + (size_t)(srow + 16)*IN_ + sf);
  g3 = *(const float4*)(p2base + (size_t)(srow + 24)*IN_ + sf);
  for(int sv=0; sv<8; ++sv){
    __syncthreads();                       // stg free; (first iter also fences P writes)
    *(float4*)&stg[srow   ][sf] = g0;
    *(float4*)&stg[srow+ 8][sf] = g1;
    *(float4*)&stg[srow+16][sf] = g2;
    *(float4*)&stg[srow+24][sf] = g3;
    if(sv < 7){
      const float* nb = p2base + (size_t)(sv+1)*32*IN_;
      g0 = *(const float4*)(nb + (size_t)(srow     )*IN_ + sf);
      g1 = *(const float4*)(nb + (size_t)(srow +  8)*IN_ + sf);
      g2 = *(const float4*)(nb + (size_t)(srow + 16)*IN_ + sf);
      g3 = *(const float4*)(nb + (size_t)(srow + 24)*IN_ + sf);
    }
    __syncthreads();                       // stg ready
    #pragma unroll
    for(int kk=0; kk<4; ++kk){
      const int vl = wk*16 + kk*4;         // local v in slice
      const int vg = sv*32 + vl;           // v within block chunk
      float4 p0 = *(const float4*)&P[rw+0][vg];
      float4 p1 = *(const float4*)&P[rw+1][vg];
      float4 p2 = *(const float4*)&P[rw+2][vg];
      float4 p3 = *(const float4*)&P[rw+3][vg];
      float4 s0v = *(const float4*)&stg[vl+0][i0];
      float4 s1v = *(const float4*)&stg[vl+1][i0];
      float4 s2v = *(const float4*)&stg[vl+2][i0];
      float4 s3v = *(const float4*)&stg[vl+3][i0];
      FMA4(d0, p0.x, s0v) FMA4(d0, p0.y, s1v) FMA4(d0, p0.z, s2v) FMA4(d0, p0.w, s3v)
      FMA4(d1, p1.x, s0v) FMA4(d1, p1.y, s1v) FMA4(d1, p1.z, s2v) FMA4(d1, p1.w, s3v)
      FMA4(d2, p2.x, s0v) FMA4(d2, p2.y, s1v) FMA4(d2, p2.z, s2v) FMA4(d2, p2.w, s3v)
      FMA4(d3, p3.x, s0v) FMA4(d3, p3.y, s1v) FMA4(d3, p3.z, s2v) FMA4(d3, p3.w, s3v)
    }
  }
  // reduce K halves through T (dead), wk0 stores to CTXP
  if(wk == 1){
    *(float4*)&T[rw+0][i0] = d0;
    *(float4*)&T[rw+1][i0] = d1;
    *(float4*)&T[rw+2][i0] = d2;
    *(float4*)&T[rw+3][i0] = d3;
  }
  __syncthreads();
  if(wk == 0){
    const int r = r0 + rw;
    float4 q0 = *(const float4*)&T[rw+0][i0];
    float4 q1 = *(const float4*)&T[rw+1][i0];
    float4 q2 = *(const float4*)&T[rw+2][i0];
    float4 q3 = *(const float4*)&T[rw+3][i0];
    d0.x+=q0.x; d0.y+=q0.y; d0.z+=q0.z; d0.w+=q0.w;
    d1.x+=q1.x; d1.y+=q1.y; d1.z+=q1.z; d1.w+=q1.w;
    d2.x+=q2.x; d2.y+=q2.y; d2.z+=q2.z; d2.w+=q2.w;
    d3.x+=q3.x; d3.y+=q3.y; d3.z+=q3.z; d3.w+=q3.w;
    *(float4*)(ws + WS_CTXP + ((size_t)vc*NR_ + r+0)*IN_ + i0) = d0;
    *(float4*)(ws + WS_CTXP + ((size_t)vc*NR_ + r+1)*IN_ + i0) = d1;
    *(float4*)(ws + WS_CTXP + ((size_t)vc*NR_ + r+2)*IN_ + i0) = d2;
    *(float4*)(ws + WS_CTXP + ((size_t)vc*NR_ + r+3)*IN_ + i0) = d3;
  }
}

// ---------------- K4: merged msg+exit (256 blocks = bu x st, 512 thr) ----------------
__global__ __launch_bounds__(512) void k_mexit(const float* __restrict__ Wv, const float* __restrict__ bv,
    const float* __restrict__ We, const float* __restrict__ be,
    const float* __restrict__ lsa, float* __restrict__ ws){
  const int bu = blockIdx.x >> 2, st = blockIdx.x & 3;
  const int b = bu >> 5, u = bu & 31;
  const int tid = threadIdx.x;
  __shared__ float xs[8][256];
  __shared__ float m2[512];
  __shared__ float invS[8];
  __shared__ float ps[4][128];
  if(tid < 64){
    int h = tid>>3, k = tid&7;
    int r = (b*8+h)*32 + u;
    float v = ws[WS_SSUMP + (size_t)r*8 + k];
    v += __shfl_xor(v,1,64); v += __shfl_xor(v,2,64); v += __shfl_xor(v,4,64);
    if(k==0) invS[h] = 1.0f / v;
  }
  {
    const int h = tid >> 6, i4 = tid & 63;
    const int r = (b*8+h)*32 + u;
    float4 s = {0,0,0,0};
    #pragma unroll
    for(int vcx=0; vcx<8; ++vcx){
      float4 t = *(const float4*)(ws + WS_CTXP + ((size_t)vcx*NR_ + r)*IN_ + i4*4);
      s.x += t.x; s.y += t.y; s.z += t.z; s.w += t.w;
    }
    float4 sc = *(const float4*)(ws + WS_SCALE + (size_t)bu*2560 + 768 + i4*4);
    s.x *= sc.x; s.y *= sc.y; s.z *= sc.z; s.w *= sc.w;
    *(float4*)(&xs[h][i4*4]) = s;
  }
  __syncthreads();
  {
    const int h = tid >> 6;
    const float4* wv = (const float4*)(Wv + (size_t)tid*256);
    const float* xp = &xs[h][0];
    float acc = 0.f;
    #pragma unroll 8
    for(int c4=0;c4<64;++c4){
      float4 w = wv[c4];
      acc += w.x*xp[c4*4]+w.y*xp[c4*4+1]+w.z*xp[c4*4+2]+w.w*xp[c4*4+3];
    }
    m2[tid] = (acc*invS[tid>>6] + bv[tid]) * ws[WS_SCALE + (size_t)bu*2560 + 1024 + tid];
  }
  __syncthreads();
  {
    const int s = st*128 + (tid & 127), sp = tid >> 7;
    const float4* we = (const float4*)(We + (size_t)s*512 + sp*128);
    const float* mp = m2 + sp*128;
    float acc = 0.f;
    #pragma unroll 8
    for(int c4=0;c4<32;++c4){
      float4 w = we[c4];
      acc += w.x*mp[c4*4]+w.y*mp[c4*4+1]+w.z*mp[c4*4+2]+w.w*mp[c4*4+3];
    }
    ps[sp][tid&127] = acc;
  }
  __syncthreads();
  if(tid < 128){
    const int s = st*128 + tid;
    ws[WS_AO + (size_t)bu*512 + s] =
      (ps[0][tid]+ps[1][tid]+ps[2][tid]+ps[3][tid] + be[s]) * lsa[s];
  }
}

// ---------------- K5: FFN layernorm + W1 + gelu + scale2 (256 blocks) ----------------
__global__ __launch_bounds__(256) void k_ffn1(const float* __restrict__ lg, const float* __restrict__ lb,
    const float* __restrict__ W1, const float* __restrict__ b1, float* __restrict__ ws){
  const int bu = blockIdx.x >> 2, ot = blockIdx.x & 3;
  const int tid = threadIdx.x, wave = tid>>6, lane = tid&63;
  __shared__ float xr[512];
  __shared__ float rsm[4], rqm[4];
  __shared__ float ps[2][128];
  float2 x2 = *(const float2*)(ws + WS_AO + (size_t)bu*512 + tid*2);
  float s = x2.x+x2.y, q = x2.x*x2.x+x2.y*x2.y;
  s = wsum(s); q = wsum(q);
  if(lane==0){ rsm[wave]=s; rqm[wave]=q; }
  __syncthreads();
  float S=rsm[0]+rsm[1]+rsm[2]+rsm[3], Q=rqm[0]+rqm[1]+rqm[2]+rqm[3];
  float mu = S*(1.0f/512.0f);
  float rv = rsqrtf(Q*(1.0f/512.0f) - mu*mu + 1e-5f);
  const float* scal = ws + WS_SCALE + (size_t)bu*2560;
  xr[tid*2]   = ((x2.x-mu)*rv*lg[tid*2]   + lb[tid*2])   * scal[1536 + tid*2];
  xr[tid*2+1] = ((x2.y-mu)*rv*lg[tid*2+1] + lb[tid*2+1]) * scal[1536 + tid*2+1];
  __syncthreads();
  const int o = ot*128 + (tid & 127), sp = tid >> 7;
  const float4* w1 = (const float4*)(W1 + (size_t)o*512 + sp*256);
  const float* xp = xr + sp*256;
  float acc = 0.f;
  #pragma unroll 8
  for(int c4=0;c4<64;++c4){
    float4 w = w1[c4];
    acc += w.x*xp[c4*4]+w.y*xp[c4*4+1]+w.z*xp[c4*4+2]+w.w*xp[c4*4+3];
  }
  ps[sp][tid&127] = acc;
  __syncthreads();
  if(sp==0){
    float hh = ps[0][tid] + ps[1][tid] + b1[o];
    float ge = 0.5f*hh*(1.0f + erff(hh*0.70710678118654752f));
    ws[WS_H2 + (size_t)bu*512 + o] = ge * scal[2048 + o];
  }
}

// ---------------- K6: FFN W2 + residual -> out (256 blocks) ----------------
__global__ __launch_bounds__(256) void k_ffn2(const float* __restrict__ W2, const float* __restrict__ b2,
    const float* __restrict__ lsf, const float* __restrict__ ws, float* __restrict__ out){
  const int bu = blockIdx.x >> 2, st = blockIdx.x & 3;
  const int tid = threadIdx.x;
  const int s = st*128 + (tid & 127), sp = tid >> 7;
  __shared__ float ps[2][128];
  const float4* w2 = (const float4*)(W2 + (size_t)s*512 + sp*256);
  const float* hp = ws + WS_H2 + (size_t)bu*512 + sp*256;
  float acc = 0.f;
  #pragma unroll 8
  for(int c4=0;c4<64;++c4){
    float4 w = w2[c4];
    acc += w.x*hp[c4*4]+w.y*hp[c4*4+1]+w.z*hp[c4*4+2]+w.w*hp[c4*4+3];
  }
  ps[sp][tid&127] = acc;
  __syncthreads();
  if(sp==0)
    out[(size_t)bu*512 + s] = ws[WS_AO + (size_t)bu*512 + s]
                            + (ps[0][tid]+ps[1][tid] + b2[s]) * lsf[s];
}

extern "C" void kernel_launch(void* const* d_in, const int* in_sizes, int n_in,
                              void* d_out, int out_size, void* d_ws, size_t ws_size,
                              hipStream_t stream) {
  (void)in_sizes; (void)n_in; (void)out_size; (void)ws_size;
  const float* rst   = (const float*)d_in[0];
  const float* codes = (const float*)d_in[2];
  const float* snd   = (const float*)d_in[3];
  const float* ln_s_g = (const float*)d_in[4];
  const float* ln_s_b = (const float*)d_in[5];
  const float* ln_r_g = (const float*)d_in[6];
  const float* ln_r_b = (const float*)d_in[7];
  const float* Wq = (const float*)d_in[8];
  const float* bq = (const float*)d_in[9];
  const float* Cq = (const float*)d_in[10];
  const float* Wk = (const float*)d_in[11];
  const float* bk = (const float*)d_in[12];
  const float* Ck = (const float*)d_in[13];
  const float* Wv = (const float*)d_in[14];
  const float* bv = (const float*)d_in[15];
  const float* Cv = (const float*)d_in[16];
  const float* We = (const float*)d_in[17];
  const float* be = (const float*)d_in[18];
  const float* Ce = (const float*)d_in[19];
  const float* lsa = (const float*)d_in[20];
  const float* ln_f_g = (const float*)d_in[21];
  const float* ln_f_b = (const float*)d_in[22];
  const float* W1 = (const float*)d_in[23];
  const float* b1 = (const float*)d_in[24];
  const float* C1 = (const float*)d_in[25];
  const float* W2 = (const float*)d_in[26];
  const float* b2 = (const float*)d_in[27];
  const float* C2 = (const float*)d_in[28];
  const float* lsf = (const float*)d_in[29];
  float* ws  = (float*)d_ws;
  float* out = (float*)d_out;

  k_pre   <<<448, 256, 0, stream>>>(snd, ln_s_g, ln_s_b, codes, Cq, Ck, Cv, Ce, C1, C2, ws);
  k_qt    <<<512, 256, 0, stream>>>(rst, ln_r_g, ln_r_b, Wq, bq, Wk, bk, ws);
  k_scctx <<<256, 512, 0, stream>>>(ws);
  k_mexit <<<256, 512, 0, stream>>>(Wv, bv, We, be, lsa, ws);
  k_ffn1  <<<256, 256, 0, stream>>>(ln_f_g, ln_f_b, W1, b1, ws);
  k_ffn2  <<<256, 256, 0, stream>>>(W2, b2, lsf, ws, out);
}

// Round 5
// 97.597 us; speedup vs baseline: 1.4353x; 1.0479x over previous
//
#include <hip/hip_runtime.h>
#include <math.h>

#define B_ 2
#define U_ 32
#define V_ 2048
#define IN_ 256
#define ST_ 512
#define H_ 8
#define BU_ 64
#define NR_ 512

// ws layout (float offsets)
#define WS_SLN   0u          // [B][V][IN]      1048576
#define WS_SLNT  1048576u    // [B][IN][V]      1048576
#define WS_SCALE 2097152u    // [BU][2560]      163840  (q:0 k:512 v:768 e:1024 f1:1536 f2:2048)
#define WS_T     2260992u    // [NR][IN]        131072
#define WS_CB    2392064u    // [NR]            512
#define WS_SSUMP 2392576u    // [NR][8]         4096
#define WS_CTXP  2396672u    // [8][NR][IN]     1048576
#define WS_AO    3445248u    // [BU][512]       32768
#define WS_H2    3478016u    // [BU][512]       32768
#define WS_AOP   3510784u    // [4][BU][512]    131072

__device__ __forceinline__ float wsum(float v){
  #pragma unroll
  for(int m=32;m>0;m>>=1) v += __shfl_xor(v, m, 64);
  return v;
}

#define FMA4(A, t, S) { A.x += (t)*(S).x; A.y += (t)*(S).y; A.z += (t)*(S).z; A.w += (t)*(S).w; }

// ---------------- K1: fused sender-LN+transpose (blocks 0..127) and scales GEMM (blocks 128..447) ----------------
__global__ __launch_bounds__(256) void k_pre(const float* __restrict__ snd,
    const float* __restrict__ g, const float* __restrict__ bb,
    const float* __restrict__ codes,
    const float* __restrict__ Cq, const float* __restrict__ Ck, const float* __restrict__ Cv,
    const float* __restrict__ Ce, const float* __restrict__ C1, const float* __restrict__ C2,
    float* __restrict__ ws){
  __shared__ float tile[32][261];
  __shared__ float cds[8][256];
  const int tid = threadIdx.x;
  if(blockIdx.x < 128){
    const int wave = tid>>6, lane = tid&63;
    const int rowbase = blockIdx.x * 32;
    const int b = rowbase >> 11, vloc = rowbase & 2047;
    float4 gg  = *(const float4*)(g  + lane*4);
    float4 bbv = *(const float4*)(bb + lane*4);
    for(int it=0; it<8; ++it){
      int rl = it*4 + wave;
      int r  = rowbase + rl;
      float4 x = *(const float4*)(snd + (size_t)r*IN_ + lane*4);
      float s = x.x+x.y+x.z+x.w;
      float q = x.x*x.x+x.y*x.y+x.z*x.z+x.w*x.w;
      s = wsum(s); q = wsum(q);
      float mu = s*(1.0f/256.0f);
      float rv = rsqrtf(q*(1.0f/256.0f) - mu*mu + 1e-5f);
      float4 y;
      y.x = (x.x-mu)*rv*gg.x + bbv.x;
      y.y = (x.y-mu)*rv*gg.y + bbv.y;
      y.z = (x.z-mu)*rv*gg.z + bbv.z;
      y.w = (x.w-mu)*rv*gg.w + bbv.w;
      *(float4*)(ws + WS_SLN + (size_t)r*IN_ + lane*4) = y;
      tile[rl][lane*4+0] = y.x;
      tile[rl][lane*4+1] = y.y;
      tile[rl][lane*4+2] = y.z;
      tile[rl][lane*4+3] = y.w;
    }
    __syncthreads();
    const int vh = tid & 31;
    const int ibase = (tid >> 5);
    for(int it=0; it<32; ++it){
      int i = it*8 + ibase;
      ws[WS_SLNT + ((size_t)b*IN_ + i)*V_ + vloc + vh] = tile[vh][i];
    }
  } else {
    const int idx = blockIdx.x - 128;
    const int cg = idx % 40, bg = idx / 40;
    #pragma unroll
    for(int j=0;j<8;++j){
      int fi = j*256 + tid;
      cds[fi>>8][fi&255] = codes[(size_t)(bg*8)*256 + fi];
    }
    __syncthreads();
    const int q = tid & 3;
    const int col = cg*64 + (tid >> 2);
    const float* Cp; int loc;
    if(col < 512){ Cp = Cq; loc = col; }
    else if(col < 768){ Cp = Ck; loc = col - 512; }
    else if(col < 1024){ Cp = Cv; loc = col - 768; }
    else if(col < 1536){ Cp = Ce; loc = col - 1024; }
    else if(col < 2048){ Cp = C1; loc = col - 1536; }
    else { Cp = C2; loc = col - 2048; }
    const float4* wrow = (const float4*)(Cp + (size_t)loc*256 + q*64);
    float acc[8] = {0,0,0,0,0,0,0,0};
    #pragma unroll 4
    for(int i=0;i<16;++i){
      float4 w = wrow[i];
      #pragma unroll
      for(int k=0;k<8;++k){
        const float4 c = *(const float4*)(&cds[k][q*64 + i*4]);
        acc[k] += w.x*c.x + w.y*c.y + w.z*c.z + w.w*c.w;
      }
    }
    #pragma unroll
    for(int k=0;k<8;++k){
      acc[k] += __shfl_xor(acc[k], 1, 64);
      acc[k] += __shfl_xor(acc[k], 2, 64);
    }
    ws[WS_SCALE + (size_t)(bg*8 + q)*2560 + col]     = 1.0f + acc[q];
    ws[WS_SCALE + (size_t)(bg*8 + q + 4)*2560 + col] = 1.0f + acc[q+4];
  }
}

// ---------------- K2: receiver LN + q head-slice + t_k + cb (512 blocks = bu x h) ----------------
__global__ __launch_bounds__(256) void k_qt(const float* __restrict__ rst,
    const float* __restrict__ lg, const float* __restrict__ lb,
    const float* __restrict__ Wq, const float* __restrict__ bq,
    const float* __restrict__ Wk, const float* __restrict__ bk,
    float* __restrict__ ws){
  const int bu = blockIdx.x >> 3, h = blockIdx.x & 7;
  const int b = bu >> 5, u = bu & 31;
  const int r = (b*8 + h)*32 + u;
  const int tid = threadIdx.x, wave = tid>>6, lane = tid&63;
  __shared__ float xm[512];
  __shared__ float qv[64];
  __shared__ float red[4][65];
  __shared__ float rsm[4], rqm[4];
  float2 x2 = *(const float2*)(rst + (size_t)bu*512 + tid*2);
  float s = x2.x + x2.y, q = x2.x*x2.x + x2.y*x2.y;
  s = wsum(s); q = wsum(q);
  if(lane==0){ rsm[wave] = s; rqm[wave] = q; }
  __syncthreads();
  float S = rsm[0]+rsm[1]+rsm[2]+rsm[3];
  float Q = rqm[0]+rqm[1]+rqm[2]+rqm[3];
  float mu = S*(1.0f/512.0f);
  float rv = rsqrtf(Q*(1.0f/512.0f) - mu*mu + 1e-5f);
  const float* scal = ws + WS_SCALE + (size_t)bu*2560;
  xm[tid*2]   = ((x2.x-mu)*rv*lg[tid*2]   + lb[tid*2])   * scal[tid*2];
  xm[tid*2+1] = ((x2.y-mu)*rv*lg[tid*2+1] + lb[tid*2+1]) * scal[tid*2+1];
  __syncthreads();
  {
    const int o = tid & 63, sp = tid >> 6;
    const float4* wq = (const float4*)(Wq + (size_t)(h*64 + o)*512 + sp*128);
    const float* xp = xm + sp*128;
    float acc = 0.f;
    #pragma unroll 8
    for(int c4=0;c4<32;++c4){
      float4 w = wq[c4];
      acc += w.x*xp[c4*4] + w.y*xp[c4*4+1] + w.z*xp[c4*4+2] + w.w*xp[c4*4+3];
    }
    red[sp][o] = acc;
  }
  __syncthreads();
  if(tid < 64)
    qv[tid] = red[0][tid]+red[1][tid]+red[2][tid]+red[3][tid] + bq[h*64+tid];
  __syncthreads();
  if(tid < 64){
    float p = qv[tid] * bk[h*64+tid];
    p = wsum(p);
    if(tid==0) ws[WS_CB + r] = p;
  }
  {
    float acc = 0.f;
    #pragma unroll 4
    for(int d=0; d<64; ++d)
      acc += qv[d] * Wk[(size_t)(h*64+d)*256 + tid];
    ws[WS_T + (size_t)r*256 + tid] = acc * scal[512 + tid];
  }
}

// ---------------- K3: fused scores->exp->ctx v3. 256 blocks x 512 thr ----------------
// block: 16 rows x 256 v. waves: wr(0..1) row-oct x wk(0..3) K-quarter.
// T read from global (wave-uniform, scalar path) — LDS holds only stg + P.
__global__ __launch_bounds__(512) void k_scctx(const float* __restrict__ Tm, float* __restrict__ ws){
  const int rg = blockIdx.x >> 3, vc = blockIdx.x & 7;
  const int r0 = rg * 16;
  const int b  = rg >> 4;
  const int v0 = vc * 256;
  const int tid = threadIdx.x, lane = tid & 63;
  const int w  = __builtin_amdgcn_readfirstlane(tid >> 6);
  const int wr = w & 1, wk = w >> 1;
  const int rw8 = wr * 8;
  const int i0 = lane * 4;
  const int srow = tid >> 6;
  const int sf   = (tid & 63) * 4;

  __shared__ float P[16][256];     // 16KB
  __shared__ float stg[32][256];   // 32KB

  float4 a0={0,0,0,0},a1={0,0,0,0},a2={0,0,0,0},a3={0,0,0,0};
  float4 a4={0,0,0,0},a5={0,0,0,0},a6={0,0,0,0},a7={0,0,0,0};

  const float* Trow = Tm + (size_t)(r0 + rw8)*256;   // wave-uniform base

  // ================= phase 1: scores = T x sT =================
  const float* p1base = ws + WS_SLNT + (size_t)b*IN_*V_ + v0;
  float4 g0,g1,g2,g3;
  g0 = *(const float4*)(p1base + (size_t)(srow    )*V_ + sf);
  g1 = *(const float4*)(p1base + (size_t)(srow+ 8)*V_ + sf);
  g2 = *(const float4*)(p1base + (size_t)(srow+16)*V_ + sf);
  g3 = *(const float4*)(p1base + (size_t)(srow+24)*V_ + sf);
  for(int s=0; s<8; ++s){
    __syncthreads();
    *(float4*)&stg[srow   ][sf] = g0;
    *(float4*)&stg[srow+ 8][sf] = g1;
    *(float4*)&stg[srow+16][sf] = g2;
    *(float4*)&stg[srow+24][sf] = g3;
    if(s < 7){
      const float* nb = p1base + (size_t)(s+1)*32*V_;
      g0 = *(const float4*)(nb + (size_t)(srow    )*V_ + sf);
      g1 = *(const float4*)(nb + (size_t)(srow+ 8)*V_ + sf);
      g2 = *(const float4*)(nb + (size_t)(srow+16)*V_ + sf);
      g3 = *(const float4*)(nb + (size_t)(srow+24)*V_ + sf);
    }
    const int kgA = s*32 + wk*8;       // uniform
    float4 tA[8], tB[8];
    #pragma unroll
    for(int j=0;j<8;++j) tA[j] = *(const float4*)(Trow + (size_t)j*256 + kgA);
    __syncthreads();
    #pragma unroll
    for(int j=0;j<8;++j) tB[j] = *(const float4*)(Trow + (size_t)j*256 + kgA + 4);
    {
      const int kl = wk*8;
      float4 s0 = *(const float4*)&stg[kl+0][i0];
      float4 s1 = *(const float4*)&stg[kl+1][i0];
      float4 s2 = *(const float4*)&stg[kl+2][i0];
      float4 s3 = *(const float4*)&stg[kl+3][i0];
      FMA4(a0,tA[0].x,s0) FMA4(a0,tA[0].y,s1) FMA4(a0,tA[0].z,s2) FMA4(a0,tA[0].w,s3)
      FMA4(a1,tA[1].x,s0) FMA4(a1,tA[1].y,s1) FMA4(a1,tA[1].z,s2) FMA4(a1,tA[1].w,s3)
      FMA4(a2,tA[2].x,s0) FMA4(a2,tA[2].y,s1) FMA4(a2,tA[2].z,s2) FMA4(a2,tA[2].w,s3)
      FMA4(a3,tA[3].x,s0) FMA4(a3,tA[3].y,s1) FMA4(a3,tA[3].z,s2) FMA4(a3,tA[3].w,s3)
      FMA4(a4,tA[4].x,s0) FMA4(a4,tA[4].y,s1) FMA4(a4,tA[4].z,s2) FMA4(a4,tA[4].w,s3)
      FMA4(a5,tA[5].x,s0) FMA4(a5,tA[5].y,s1) FMA4(a5,tA[5].z,s2) FMA4(a5,tA[5].w,s3)
      FMA4(a6,tA[6].x,s0) FMA4(a6,tA[6].y,s1) FMA4(a6,tA[6].z,s2) FMA4(a6,tA[6].w,s3)
      FMA4(a7,tA[7].x,s0) FMA4(a7,tA[7].y,s1) FMA4(a7,tA[7].z,s2) FMA4(a7,tA[7].w,s3)
    }
    {
      const int kl = wk*8 + 4;
      float4 s0 = *(const float4*)&stg[kl+0][i0];
      float4 s1 = *(const float4*)&stg[kl+1][i0];
      float4 s2 = *(const float4*)&stg[kl+2][i0];
      float4 s3 = *(const float4*)&stg[kl+3][i0];
      FMA4(a0,tB[0].x,s0) FMA4(a0,tB[0].y,s1) FMA4(a0,tB[0].z,s2) FMA4(a0,tB[0].w,s3)
      FMA4(a1,tB[1].x,s0) FMA4(a1,tB[1].y,s1) FMA4(a1,tB[1].z,s2) FMA4(a1,tB[1].w,s3)
      FMA4(a2,tB[2].x,s0) FMA4(a2,tB[2].y,s1) FMA4(a2,tB[2].z,s2) FMA4(a2,tB[2].w,s3)
      FMA4(a3,tB[3].x,s0) FMA4(a3,tB[3].y,s1) FMA4(a3,tB[3].z,s2) FMA4(a3,tB[3].w,s3)
      FMA4(a4,tB[4].x,s0) FMA4(a4,tB[4].y,s1) FMA4(a4,tB[4].z,s2) FMA4(a4,tB[4].w,s3)
      FMA4(a5,tB[5].x,s0) FMA4(a5,tB[5].y,s1) FMA4(a5,tB[5].z,s2) FMA4(a5,tB[5].w,s3)
      FMA4(a6,tB[6].x,s0) FMA4(a6,tB[6].y,s1) FMA4(a6,tB[6].z,s2) FMA4(a6,tB[6].w,s3)
      FMA4(a7,tB[7].x,s0) FMA4(a7,tB[7].y,s1) FMA4(a7,tB[7].z,s2) FMA4(a7,tB[7].w,s3)
    }
  }
  // ---- reduce 4 K-quarters: wk0->P, wk1->stg[0:16), wk2->stg[16:32), wk3 finishes ----
  __syncthreads();
  if(wk == 0){
    *(float4*)&P[rw8+0][i0]=a0; *(float4*)&P[rw8+1][i0]=a1;
    *(float4*)&P[rw8+2][i0]=a2; *(float4*)&P[rw8+3][i0]=a3;
    *(float4*)&P[rw8+4][i0]=a4; *(float4*)&P[rw8+5][i0]=a5;
    *(float4*)&P[rw8+6][i0]=a6; *(float4*)&P[rw8+7][i0]=a7;
  } else if(wk == 1){
    *(float4*)&stg[rw8+0][i0]=a0; *(float4*)&stg[rw8+1][i0]=a1;
    *(float4*)&stg[rw8+2][i0]=a2; *(float4*)&stg[rw8+3][i0]=a3;
    *(float4*)&stg[rw8+4][i0]=a4; *(float4*)&stg[rw8+5][i0]=a5;
    *(float4*)&stg[rw8+6][i0]=a6; *(float4*)&stg[rw8+7][i0]=a7;
  } else if(wk == 2){
    *(float4*)&stg[16+rw8+0][i0]=a0; *(float4*)&stg[16+rw8+1][i0]=a1;
    *(float4*)&stg[16+rw8+2][i0]=a2; *(float4*)&stg[16+rw8+3][i0]=a3;
    *(float4*)&stg[16+rw8+4][i0]=a4; *(float4*)&stg[16+rw8+5][i0]=a5;
    *(float4*)&stg[16+rw8+6][i0]=a6; *(float4*)&stg[16+rw8+7][i0]=a7;
  }
  __syncthreads();
  if(wk == 3){
    float4 av[8] = {a0,a1,a2,a3,a4,a5,a6,a7};
    #pragma unroll
    for(int j=0;j<8;++j){
      const int r = r0 + rw8 + j;
      const float cb = ws[WS_CB + r];
      float4 q0 = *(const float4*)&P[rw8+j][i0];
      float4 q1 = *(const float4*)&stg[rw8+j][i0];
      float4 q2 = *(const float4*)&stg[16+rw8+j][i0];
      float4 e;
      e.x = __expf((av[j].x+q0.x+q1.x+q2.x+cb)*0.125f);
      e.y = __expf((av[j].y+q0.y+q1.y+q2.y+cb)*0.125f);
      e.z = __expf((av[j].z+q0.z+q1.z+q2.z+cb)*0.125f);
      e.w = __expf((av[j].w+q0.w+q1.w+q2.w+cb)*0.125f);
      *(float4*)&P[rw8+j][i0] = e;
      float ss = wsum(e.x+e.y+e.z+e.w);
      if(lane==0) ws[WS_SSUMP + (size_t)r*8 + vc] = ss;
    }
  }

  // ================= phase 2: ctx = P x SL =================
  a0=make_float4(0,0,0,0); a1=a0; a2=a0; a3=a0; a4=a0; a5=a0; a6=a0; a7=a0;
  const float* p2base = ws + WS_SLN + ((size_t)b*V_ + v0)*IN_;
  g0 = *(const float4*)(p2base + (size_t)(srow    )*IN_ + sf);
  g1 = *(const float4*)(p2base + (size_t)(srow+ 8)*IN_ + sf);
  g2 = *(const float4*)(p2base + (size_t)(srow+16)*IN_ + sf);
  g3 = *(const float4*)(p2base + (size_t)(srow+24)*IN_ + sf);
  for(int sv=0; sv<8; ++sv){
    __syncthreads();     // first pass: P exp-write + stg partial reads complete
    *(float4*)&stg[srow   ][sf] = g0;
    *(float4*)&stg[srow+ 8][sf] = g1;
    *(float4*)&stg[srow+16][sf] = g2;
    *(float4*)&stg[srow+24][sf] = g3;
    if(sv < 7){
      const float* nb = p2base + (size_t)(sv+1)*32*IN_;
      g0 = *(const float4*)(nb + (size_t)(srow    )*IN_ + sf);
      g1 = *(const float4*)(nb + (size_t)(srow+ 8)*IN_ + sf);
      g2 = *(const float4*)(nb + (size_t)(srow+16)*IN_ + sf);
      g3 = *(const float4*)(nb + (size_t)(srow+24)*IN_ + sf);
    }
    __syncthreads();
    {
      const int vl = wk*8, vg = sv*32 + vl;
      float4 p0_ = *(const float4*)&P[rw8+0][vg];
      float4 p1_ = *(const float4*)&P[rw8+1][vg];
      float4 p2_ = *(const float4*)&P[rw8+2][vg];
      float4 p3_ = *(const float4*)&P[rw8+3][vg];
      float4 p4_ = *(const float4*)&P[rw8+4][vg];
      float4 p5_ = *(const float4*)&P[rw8+5][vg];
      float4 p6_ = *(const float4*)&P[rw8+6][vg];
      float4 p7_ = *(const float4*)&P[rw8+7][vg];
      float4 s0 = *(const float4*)&stg[vl+0][i0];
      float4 s1 = *(const float4*)&stg[vl+1][i0];
      float4 s2 = *(const float4*)&stg[vl+2][i0];
      float4 s3 = *(const float4*)&stg[vl+3][i0];
      FMA4(a0,p0_.x,s0) FMA4(a0,p0_.y,s1) FMA4(a0,p0_.z,s2) FMA4(a0,p0_.w,s3)
      FMA4(a1,p1_.x,s0) FMA4(a1,p1_.y,s1) FMA4(a1,p1_.z,s2) FMA4(a1,p1_.w,s3)
      FMA4(a2,p2_.x,s0) FMA4(a2,p2_.y,s1) FMA4(a2,p2_.z,s2) FMA4(a2,p2_.w,s3)
      FMA4(a3,p3_.x,s0) FMA4(a3,p3_.y,s1) FMA4(a3,p3_.z,s2) FMA4(a3,p3_.w,s3)
      FMA4(a4,p4_.x,s0) FMA4(a4,p4_.y,s1) FMA4(a4,p4_.z,s2) FMA4(a4,p4_.w,s3)
      FMA4(a5,p5_.x,s0) FMA4(a5,p5_.y,s1) FMA4(a5,p5_.z,s2) FMA4(a5,p5_.w,s3)
      FMA4(a6,p6_.x,s0) FMA4(a6,p6_.y,s1) FMA4(a6,p6_.z,s2) FMA4(a6,p6_.w,s3)
      FMA4(a7,p7_.x,s0) FMA4(a7,p7_.y,s1) FMA4(a7,p7_.z,s2) FMA4(a7,p7_.w,s3)
    }
    {
      const int vl = wk*8 + 4, vg = sv*32 + vl;
      float4 p0_ = *(const float4*)&P[rw8+0][vg];
      float4 p1_ = *(const float4*)&P[rw8+1][vg];
      float4 p2_ = *(const float4*)&P[rw8+2][vg];
      float4 p3_ = *(const float4*)&P[rw8+3][vg];
      float4 p4_ = *(const float4*)&P[rw8+4][vg];
      float4 p5_ = *(const float4*)&P[rw8+5][vg];
      float4 p6_ = *(const float4*)&P[rw8+6][vg];
      float4 p7_ = *(const float4*)&P[rw8+7][vg];
      float4 s0 = *(const float4*)&stg[vl+0][i0];
      float4 s1 = *(const float4*)&stg[vl+1][i0];
      float4 s2 = *(const float4*)&stg[vl+2][i0];
      float4 s3 = *(const float4*)&stg[vl+3][i0];
      FMA4(a0,p0_.x,s0) FMA4(a0,p0_.y,s1) FMA4(a0,p0_.z,s2) FMA4(a0,p0_.w,s3)
      FMA4(a1,p1_.x,s0) FMA4(a1,p1_.y,s1) FMA4(a1,p1_.z,s2) FMA4(a1,p1_.w,s3)
      FMA4(a2,p2_.x,s0) FMA4(a2,p2_.y,s1) FMA4(a2,p2_.z,s2) FMA4(a2,p2_.w,s3)
      FMA4(a3,p3_.x,s0) FMA4(a3,p3_.y,s1) FMA4(a3,p3_.z,s2) FMA4(a3,p3_.w,s3)
      FMA4(a4,p4_.x,s0) FMA4(a4,p4_.y,s1) FMA4(a4,p4_.z,s2) FMA4(a4,p4_.w,s3)
      FMA4(a5,p5_.x,s0) FMA4(a5,p5_.y,s1) FMA4(a5,p5_.z,s2) FMA4(a5,p5_.w,s3)
      FMA4(a6,p6_.x,s0) FMA4(a6,p6_.y,s1) FMA4(a6,p6_.z,s2) FMA4(a6,p6_.w,s3)
      FMA4(a7,p7_.x,s0) FMA4(a7,p7_.y,s1) FMA4(a7,p7_.z,s2) FMA4(a7,p7_.w,s3)
    }
  }
  // ---- reduce 4 v-quarters and store CTXP ----
  __syncthreads();
  if(wk == 0){
    *(float4*)&P[rw8+0][i0]=a0; *(float4*)&P[rw8+1][i0]=a1;
    *(float4*)&P[rw8+2][i0]=a2; *(float4*)&P[rw8+3][i0]=a3;
    *(float4*)&P[rw8+4][i0]=a4; *(float4*)&P[rw8+5][i0]=a5;
    *(float4*)&P[rw8+6][i0]=a6; *(float4*)&P[rw8+7][i0]=a7;
  } else if(wk == 1){
    *(float4*)&stg[rw8+0][i0]=a0; *(float4*)&stg[rw8+1][i0]=a1;
    *(float4*)&stg[rw8+2][i0]=a2; *(float4*)&stg[rw8+3][i0]=a3;
    *(float4*)&stg[rw8+4][i0]=a4; *(float4*)&stg[rw8+5][i0]=a5;
    *(float4*)&stg[rw8+6][i0]=a6; *(float4*)&stg[rw8+7][i0]=a7;
  } else if(wk == 2){
    *(float4*)&stg[16+rw8+0][i0]=a0; *(float4*)&stg[16+rw8+1][i0]=a1;
    *(float4*)&stg[16+rw8+2][i0]=a2; *(float4*)&stg[16+rw8+3][i0]=a3;
    *(float4*)&stg[16+rw8+4][i0]=a4; *(float4*)&stg[16+rw8+5][i0]=a5;
    *(float4*)&stg[16+rw8+6][i0]=a6; *(float4*)&stg[16+rw8+7][i0]=a7;
  }
  __syncthreads();
  if(wk == 3){
    float4 av[8] = {a0,a1,a2,a3,a4,a5,a6,a7};
    #pragma unroll
    for(int j=0;j<8;++j){
      const int r = r0 + rw8 + j;
      float4 q0 = *(const float4*)&P[rw8+j][i0];
      float4 q1 = *(const float4*)&stg[rw8+j][i0];
      float4 q2 = *(const float4*)&stg[16+rw8+j][i0];
      float4 d;
      d.x = av[j].x+q0.x+q1.x+q2.x;
      d.y = av[j].y+q0.y+q1.y+q2.y;
      d.z = av[j].z+q0.z+q1.z+q2.z;
      d.w = av[j].w+q0.w+q1.w+q2.w;
      *(float4*)(ws + WS_CTXP + ((size_t)vc*NR_ + r)*IN_ + i0) = d;
    }
  }
}

// ---------------- K4: msg+exit v2, column-split We -> AO partials (256 blocks = bu x st, 512 thr) ----------------
__global__ __launch_bounds__(512) void k_mexit(const float* __restrict__ Wv, const float* __restrict__ bv,
    const float* __restrict__ We, float* __restrict__ ws){
  const int bu = blockIdx.x >> 2, st = blockIdx.x & 3;
  const int b = bu >> 5, u = bu & 31;
  const int tid = threadIdx.x;
  __shared__ float xs[2][256];     // ctx for the 2 heads feeding this m2 slice
  __shared__ float m2s[128];
  __shared__ float ps[4][128];
  __shared__ float invS[2];
  if(tid < 2){
    const int r = (b*8 + st*2 + tid)*32 + u;
    float v = 0.f;
    #pragma unroll
    for(int k=0;k<8;++k) v += ws[WS_SSUMP + (size_t)r*8 + k];
    invS[tid] = 1.0f / v;
  }
  // phase A: xs[hh][i] = (sum_vc CTXP) * scale_v[i]   (invS deferred)
  {
    const int hh = tid >> 8, i = tid & 255;
    const int r = (b*8 + st*2 + hh)*32 + u;
    float s = 0.f;
    #pragma unroll
    for(int vcx=0; vcx<8; ++vcx)
      s += ws[WS_CTXP + ((size_t)vcx*NR_ + r)*IN_ + i];
    xs[hh][i] = s * ws[WS_SCALE + (size_t)bu*2560 + 768 + i];
  }
  __syncthreads();
  // phase B: m2 slice [st*128, +128): thread (sp,lo)
  {
    const int lo = tid & 127, sp = tid >> 7;
    const int o = st*128 + lo;
    const float4* wv = (const float4*)(Wv + (size_t)o*256 + sp*64);
    const float* xp = &xs[lo>>6][sp*64];
    float acc = 0.f;
    #pragma unroll
    for(int c4=0;c4<16;++c4){
      float4 w = wv[c4];
      acc += w.x*xp[c4*4]+w.y*xp[c4*4+1]+w.z*xp[c4*4+2]+w.w*xp[c4*4+3];
    }
    ps[sp][lo] = acc;
  }
  __syncthreads();
  if(tid < 128){
    const int o = st*128 + tid;
    m2s[tid] = ((ps[0][tid]+ps[1][tid]+ps[2][tid]+ps[3][tid]) * invS[tid>>6] + bv[o])
               * ws[WS_SCALE + (size_t)bu*2560 + 1024 + o];
  }
  __syncthreads();
  // phase C: partial AO over this i-slice of We (one output row per thread)
  {
    const float4* we = (const float4*)(We + (size_t)tid*512 + st*128);
    float acc = 0.f;
    #pragma unroll 8
    for(int c4=0;c4<32;++c4){
      float4 w = we[c4];
      acc += w.x*m2s[c4*4]+w.y*m2s[c4*4+1]+w.z*m2s[c4*4+2]+w.w*m2s[c4*4+3];
    }
    ws[WS_AOP + ((size_t)st*BU_ + bu)*512 + tid] = acc;
  }
}

// ---------------- K5: AO reduce + FFN layernorm + W1 + gelu + scale2 (256 blocks) ----------------
__global__ __launch_bounds__(256) void k_ffn1(const float* __restrict__ be, const float* __restrict__ lsa,
    const float* __restrict__ lg, const float* __restrict__ lb,
    const float* __restrict__ W1, const float* __restrict__ b1, float* __restrict__ ws){
  const int bu = blockIdx.x >> 2, ot = blockIdx.x & 3;
  const int tid = threadIdx.x, wave = tid>>6, lane = tid&63;
  __shared__ float xr[512];
  __shared__ float rsm[4], rqm[4];
  __shared__ float ps[2][128];
  // AO reduce: 2 elements/thread
  const int s2 = tid*2;
  float2 x2;
  {
    const float* aop = ws + WS_AOP;
    float ax = aop[((size_t)0*BU_+bu)*512+s2] + aop[((size_t)1*BU_+bu)*512+s2]
             + aop[((size_t)2*BU_+bu)*512+s2] + aop[((size_t)3*BU_+bu)*512+s2];
    float ay = aop[((size_t)0*BU_+bu)*512+s2+1] + aop[((size_t)1*BU_+bu)*512+s2+1]
             + aop[((size_t)2*BU_+bu)*512+s2+1] + aop[((size_t)3*BU_+bu)*512+s2+1];
    x2.x = (ax + be[s2])   * lsa[s2];
    x2.y = (ay + be[s2+1]) * lsa[s2+1];
    *(float2*)(ws + WS_AO + (size_t)bu*512 + s2) = x2;   // residual for ffn2
  }
  float s = x2.x+x2.y, q = x2.x*x2.x+x2.y*x2.y;
  s = wsum(s); q = wsum(q);
  if(lane==0){ rsm[wave]=s; rqm[wave]=q; }
  __syncthreads();
  float S=rsm[0]+rsm[1]+rsm[2]+rsm[3], Q=rqm[0]+rqm[1]+rqm[2]+rqm[3];
  float mu = S*(1.0f/512.0f);
  float rv = rsqrtf(Q*(1.0f/512.0f) - mu*mu + 1e-5f);
  const float* scal = ws + WS_SCALE + (size_t)bu*2560;
  xr[s2]   = ((x2.x-mu)*rv*lg[s2]   + lb[s2])   * scal[1536 + s2];
  xr[s2+1] = ((x2.y-mu)*rv*lg[s2+1] + lb[s2+1]) * scal[1536 + s2+1];
  __syncthreads();
  const int o = ot*128 + (tid & 127), sp = tid >> 7;
  const float4* w1 = (const float4*)(W1 + (size_t)o*512 + sp*256);
  const float* xp = xr + sp*256;
  float acc = 0.f;
  #pragma unroll 8
  for(int c4=0;c4<64;++c4){
    float4 w = w1[c4];
    acc += w.x*xp[c4*4]+w.y*xp[c4*4+1]+w.z*xp[c4*4+2]+w.w*xp[c4*4+3];
  }
  ps[sp][tid&127] = acc;
  __syncthreads();
  if(sp==0){
    float hh = ps[0][tid] + ps[1][tid] + b1[o];
    float ge = 0.5f*hh*(1.0f + erff(hh*0.70710678118654752f));
    ws[WS_H2 + (size_t)bu*512 + o] = ge * scal[2048 + o];
  }
}

// ---------------- K6: FFN W2 + residual -> out (256 blocks) ----------------
__global__ __launch_bounds__(256) void k_ffn2(const float* __restrict__ W2, const float* __restrict__ b2,
    const float* __restrict__ lsf, const float* __restrict__ ws, float* __restrict__ out){
  const int bu = blockIdx.x >> 2, st = blockIdx.x & 3;
  const int tid = threadIdx.x;
  const int s = st*128 + (tid & 127), sp = tid >> 7;
  __shared__ float ps[2][128];
  const float4* w2 = (const float4*)(W2 + (size_t)s*512 + sp*256);
  const float* hp = ws + WS_H2 + (size_t)bu*512 + sp*256;
  float acc = 0.f;
  #pragma unroll 8
  for(int c4=0;c4<64;++c4){
    float4 w = w2[c4];
    acc += w.x*hp[c4*4]+w.y*hp[c4*4+1]+w.z*hp[c4*4+2]+w.w*hp[c4*4+3];
  }
  ps[sp][tid&127] = acc;
  __syncthreads();
  if(sp==0)
    out[(size_t)bu*512 + s] = ws[WS_AO + (size_t)bu*512 + s]
                            + (ps[0][tid]+ps[1][tid] + b2[s]) * lsf[s];
}

extern "C" void kernel_launch(void* const* d_in, const int* in_sizes, int n_in,
                              void* d_out, int out_size, void* d_ws, size_t ws_size,
                              hipStream_t stream) {
  (void)in_sizes; (void)n_in; (void)out_size; (void)ws_size;
  const float* rst   = (const float*)d_in[0];
  const float* codes = (const float*)d_in[2];
  const float* snd   = (const float*)d_in[3];
  const float* ln_s_g = (const float*)d_in[4];
  const float* ln_s_b = (const float*)d_in[5];
  const float* ln_r_g = (const float*)d_in[6];
  const float* ln_r_b = (const float*)d_in[7];
  const float* Wq = (const float*)d_in[8];
  const float* bq = (const float*)d_in[9];
  const float* Cq = (const float*)d_in[10];
  const float* Wk = (const float*)d_in[11];
  const float* bk = (const float*)d_in[12];
  const float* Ck = (const float*)d_in[13];
  const float* Wv = (const float*)d_in[14];
  const float* bv = (const float*)d_in[15];
  const float* Cv = (const float*)d_in[16];
  const float* We = (const float*)d_in[17];
  const float* be = (const float*)d_in[18];
  const float* Ce = (const float*)d_in[19];
  const float* lsa = (const float*)d_in[20];
  const float* ln_f_g = (const float*)d_in[21];
  const float* ln_f_b = (const float*)d_in[22];
  const float* W1 = (const float*)d_in[23];
  const float* b1 = (const float*)d_in[24];
  const float* C1 = (const float*)d_in[25];
  const float* W2 = (const float*)d_in[26];
  const float* b2 = (const float*)d_in[27];
  const float* C2 = (const float*)d_in[28];
  const float* lsf = (const float*)d_in[29];
  float* ws  = (float*)d_ws;
  float* out = (float*)d_out;

  k_pre   <<<448, 256, 0, stream>>>(snd, ln_s_g, ln_s_b, codes, Cq, Ck, Cv, Ce, C1, C2, ws);
  k_qt    <<<512, 256, 0, stream>>>(rst, ln_r_g, ln_r_b, Wq, bq, Wk, bk, ws);
  k_scctx <<<256, 512, 0, stream>>>((const float*)(ws + WS_T), ws);
  k_mexit <<<256, 512, 0, stream>>>(Wv, bv, We, ws);
  k_ffn1  <<<256, 256, 0, stream>>>(be, lsa, ln_f_g, ln_f_b, W1, b1, ws);
  k_ffn2  <<<256, 256, 0, stream>>>(W2, b2, lsf, ws, out);
}